// Round 7
// baseline (302.445 us; speedup 1.0000x reference)
//
#include <hip/hip_runtime.h>

#define T_STEPS 301
#define IN_DIM  40
#define LOG2E   1.44269504088896340736f

typedef __attribute__((ext_vector_type(8))) _Float16 f16x8;
typedef __attribute__((ext_vector_type(4))) float f32x4;
typedef unsigned short ushort_t;
typedef unsigned int uint_t;

__device__ __forceinline__ f16x8 cvt8h(const float4 a, const float4 b) {
  f16x8 r;
  r[0] = (_Float16)a.x; r[1] = (_Float16)a.y; r[2] = (_Float16)a.z; r[3] = (_Float16)a.w;
  r[4] = (_Float16)b.x; r[5] = (_Float16)b.y; r[6] = (_Float16)b.z; r[7] = (_Float16)b.w;
  return r;
}

// z inputs pre-scaled by log2e (2*log2e for g-gate) -> exp2-based activations.
__device__ __forceinline__ float lstm_act(float zi, float zf, float zg, float zo, float& cc) {
  const float ig = __builtin_amdgcn_rcpf(1.0f + __builtin_amdgcn_exp2f(-zi));
  const float fg = __builtin_amdgcn_rcpf(1.0f + __builtin_amdgcn_exp2f(-zf));
  const float gg = 1.0f - 2.0f * __builtin_amdgcn_rcpf(1.0f + __builtin_amdgcn_exp2f(zg));
  const float og = __builtin_amdgcn_rcpf(1.0f + __builtin_amdgcn_exp2f(-zo));
  cc = fg * cc + ig * gg;
  const float tc = 1.0f - 2.0f * __builtin_amdgcn_rcpf(1.0f + __builtin_amdgcn_exp2f(cc * (2.0f * LOG2E)));
  return og * tc;
}

// 1024 blocks x 256 thr (4 waves) -> 4 independent blocks/CU = 4 chains/SIMD.
// Block = 4 batches. A/D row = 4*s + q (batch s, time-offset q). One xproj MFMA
// volley per 4 steps fills zacc regs 0..3 with xw[t..t+3] (full M=16); each step's
// recurrent MFMA updates only reg q (h rows 4s+q' are zero for q'!=q). Lane-group
// g16 = batch -> ONE cell state per thread, 5 transcendentals/step.
// h buffers: buf0 carries rows {0,2} mod 4, buf1 rows {1,3}; each row h-written at
// step q-1 and zeroed at q+1 -> pass-through rows provably zero every step.
__global__ __launch_bounds__(256, 4)
void lstm_q4(const float* __restrict__ x, const float* __restrict__ w_ih,
             const float* __restrict__ w_hh, const float* __restrict__ b_ih,
             const float* __restrict__ b_hh, const float* __restrict__ w_clf,
             const float* __restrict__ b_clf, float* __restrict__ out) {
  __shared__ ushort_t hbuf[2][16][64];   // 4 KB, fp16 h
  __shared__ float red[64][5];

  const int tid = threadIdx.x;
  const int l   = tid & 63;
  const int w   = tid >> 6;        // n-strip id (wave)
  const int r15 = l & 15;          // A/D-row role; D-col role
  const int g16 = l >> 4;          // k-group role; D row-group = BATCH
  const int n   = w * 16 + r15;    // hidden index (B/D col space)

  const float gscale[4] = {LOG2E, LOG2E, 2.0f * LOG2E, LOG2E};

  // ---- weights in registers (fp16, prescaled) ----
  f16x8 whh[4][2], wih[4][2];
  float biasv[4];
#pragma unroll
  for (int c = 0; c < 4; ++c) {
    const float s = gscale[c];
    const float* wr = w_hh + (size_t)(c * 64 + n) * 64;
#pragma unroll
    for (int kc = 0; kc < 2; ++kc) {
      float4 v0 = *(const float4*)(wr + kc * 32 + g16 * 8);
      float4 v1 = *(const float4*)(wr + kc * 32 + g16 * 8 + 4);
      v0.x *= s; v0.y *= s; v0.z *= s; v0.w *= s;
      v1.x *= s; v1.y *= s; v1.z *= s; v1.w *= s;
      whh[c][kc] = cvt8h(v0, v1);
    }
    const float* wir = w_ih + (size_t)(c * 64 + n) * IN_DIM;
    {
      float4 v0 = *(const float4*)(wir + g16 * 8);   // k = 8*g16..+8 <= 31
      float4 v1 = *(const float4*)(wir + g16 * 8 + 4);
      v0.x *= s; v0.y *= s; v0.z *= s; v0.w *= s;
      v1.x *= s; v1.y *= s; v1.z *= s; v1.w *= s;
      wih[c][0] = cvt8h(v0, v1);
    }
    {
      float4 v0 = make_float4(0, 0, 0, 0), v1 = make_float4(0, 0, 0, 0);
      if (g16 == 0) {                                // k = 32..39
        v0 = *(const float4*)(wir + 32);
        v1 = *(const float4*)(wir + 36);
        v0.x *= s; v0.y *= s; v0.z *= s; v0.w *= s;
        v1.x *= s; v1.y *= s; v1.z *= s; v1.w *= s;
      }
      wih[c][1] = cvt8h(v0, v1);
    }
    biasv[c] = (b_ih[c * 64 + n] + b_hh[c * 64 + n]) * s;
  }

  // zero both h buffers
  {
    uint_t* hz = (uint_t*)&hbuf[0][0][0];
    for (int i = tid; i < 1024; i += 256) hz[i] = 0;
  }
  __syncthreads();

  // x A-provider mapping: this lane provides A row r15 = 4*s_a + q_a
  const int s_a = r15 >> 2;
  const int q_a = r15 & 3;
  const float* xbase = x + (size_t)(blockIdx.x * 4 + s_a) * T_STEPS * IN_DIM;

  // prefetch x for pack 0 (times q_a)
  float4 xa0, xa1, xb0 = make_float4(0, 0, 0, 0), xb1 = make_float4(0, 0, 0, 0);
  {
    const float* xp = xbase + q_a * IN_DIM + g16 * 8;
    xa0 = *(const float4*)xp;
    xa1 = *(const float4*)(xp + 4);
    if (g16 == 0) {
      xb0 = *(const float4*)(xbase + q_a * IN_DIM + 32);
      xb1 = *(const float4*)(xbase + q_a * IN_DIM + 36);
    }
  }

  f32x4 zacc[4];
  float cc = 0.f, a = 0.f;
  float wc_cur = w_clf[n];
  const int wrb = g16 * 4;         // this thread's D/write row base (batch g16)

  // loop-invariant LDS addresses (reads: A row r15; writes: batch row base)
  ushort_t* const rd0 = &hbuf[0][r15][g16 * 8];
  ushort_t* const rd1 = &hbuf[1][r15][g16 * 8];

#define QSTEP(Q, RB, WB, WROW, ZROW)                                              \
  {                                                                               \
    const int t = t0 + Q;                                                         \
    f16x8 ah0 = *(const f16x8*)(RB);                                              \
    f16x8 ah1 = *(const f16x8*)((RB) + 32);                                       \
    _Pragma("unroll")                                                             \
    for (int c = 0; c < 4; ++c) {                                                 \
      zacc[c] = __builtin_amdgcn_mfma_f32_16x16x32_f16(ah0, whh[c][0], zacc[c], 0, 0, 0); \
      zacc[c] = __builtin_amdgcn_mfma_f32_16x16x32_f16(ah1, whh[c][1], zacc[c], 0, 0, 0); \
    }                                                                             \
    const float wcn = (t + 1 < T_STEPS) ? w_clf[(t + 1) * 64 + n] : wc_cur;       \
    const float h = lstm_act(zacc[0][Q], zacc[1][Q], zacc[2][Q], zacc[3][Q], cc); \
    a += h * wc_cur;                                                              \
    wc_cur = wcn;                                                                 \
    union { _Float16 hf; ushort_t u; } cv;                                        \
    cv.hf = (_Float16)h;                                                          \
    hbuf[WB][wrb + WROW][n] = cv.u;                                               \
    hbuf[WB][wrb + ZROW][n] = 0;                                                  \
    asm volatile("s_waitcnt lgkmcnt(0)\n\ts_barrier" ::: "memory");               \
  }

  for (int p = 0; p <= 75; ++p) {
    const int t0 = 4 * p;
    // ---- q = 0 (t0 even: read buf0, write buf1) + xproj volley for the pack ----
    {
      f16x8 ah0 = *(const f16x8*)(rd0);
      f16x8 ah1 = *(const f16x8*)(rd0 + 32);
      const f16x8 xf0 = cvt8h(xa0, xa1);
      const f16x8 xf1 = cvt8h(xb0, xb1);
#pragma unroll
      for (int c = 0; c < 4; ++c) {
        zacc[c] = (f32x4){biasv[c], biasv[c], biasv[c], biasv[c]};
        zacc[c] = __builtin_amdgcn_mfma_f32_16x16x32_f16(xf0, wih[c][0], zacc[c], 0, 0, 0);
        zacc[c] = __builtin_amdgcn_mfma_f32_16x16x32_f16(xf1, wih[c][1], zacc[c], 0, 0, 0);
      }
      // prefetch x for next pack (stays in flight across barriers)
      if (t0 + 4 < T_STEPS) {
        const int tq = t0 + 4 + q_a;
        const int tm = (tq <= T_STEPS - 1) ? tq : T_STEPS - 1;
        const float* xp = xbase + tm * IN_DIM + g16 * 8;
        xa0 = *(const float4*)xp;
        xa1 = *(const float4*)(xp + 4);
        if (g16 == 0) {
          xb0 = *(const float4*)(xbase + tm * IN_DIM + 32);
          xb1 = *(const float4*)(xbase + tm * IN_DIM + 36);
        }
      }
#pragma unroll
      for (int c = 0; c < 4; ++c) {
        zacc[c] = __builtin_amdgcn_mfma_f32_16x16x32_f16(ah0, whh[c][0], zacc[c], 0, 0, 0);
        zacc[c] = __builtin_amdgcn_mfma_f32_16x16x32_f16(ah1, whh[c][1], zacc[c], 0, 0, 0);
      }
      const float wcn = (t0 + 1 < T_STEPS) ? w_clf[(t0 + 1) * 64 + n] : wc_cur;
      const float h = lstm_act(zacc[0][0], zacc[1][0], zacc[2][0], zacc[3][0], cc);
      a += h * wc_cur;
      wc_cur = wcn;
      union { _Float16 hf; ushort_t u; } cv;
      cv.hf = (_Float16)h;
      hbuf[1][wrb + 1][n] = cv.u;
      hbuf[1][wrb + 3][n] = 0;
      if (t0 + 1 >= T_STEPS) break;    // t0 == 300: done (uniform across block)
      asm volatile("s_waitcnt lgkmcnt(0)\n\ts_barrier" ::: "memory");
    }
    QSTEP(1, rd1, 0, 2, 0)    // t odd:  read buf1 row 1, write buf0
    QSTEP(2, rd0, 1, 3, 1)    // t even: read buf0 row 2, write buf1
    QSTEP(3, rd1, 0, 0, 2)    // t odd:  read buf1 row 3, write buf0
  }
#undef QSTEP

  // ---- epilogue: reduce classifier partials over hidden dim ----
  red[n][g16] = a;
  __syncthreads();
  if (tid < 4) {
    float s = b_clf[0];
#pragma unroll 8
    for (int j = 0; j < 64; ++j) s += red[j][tid];
    out[blockIdx.x * 4 + tid] = s;
  }
}

extern "C" void kernel_launch(void* const* d_in, const int* in_sizes, int n_in,
                              void* d_out, int out_size, void* d_ws, size_t ws_size,
                              hipStream_t stream) {
  const float* x     = (const float*)d_in[0];
  const float* w_ih  = (const float*)d_in[1];
  const float* w_hh  = (const float*)d_in[2];
  const float* b_ih  = (const float*)d_in[3];
  const float* b_hh  = (const float*)d_in[4];
  const float* w_clf = (const float*)d_in[5];
  const float* b_clf = (const float*)d_in[6];
  float* out = (float*)d_out;

  lstm_q4<<<1024, 256, 0, stream>>>(x, w_ih, w_hh, b_ih, b_hh, w_clf, b_clf, out);
}

// Round 8
// 191.311 us; speedup vs baseline: 1.5809x; 1.5809x over previous
//
#include <hip/hip_runtime.h>

#define T_STEPS 301
#define IN_DIM  40
#define LOG2E   1.44269504088896340736f

typedef __attribute__((ext_vector_type(8))) _Float16 f16x8;
typedef __attribute__((ext_vector_type(4))) float f32x4;
typedef unsigned short ushort_t;
typedef unsigned int uint_t;

__device__ __forceinline__ f16x8 cvt8h(const float4 a, const float4 b) {
  f16x8 r;
  r[0] = (_Float16)a.x; r[1] = (_Float16)a.y; r[2] = (_Float16)a.z; r[3] = (_Float16)a.w;
  r[4] = (_Float16)b.x; r[5] = (_Float16)b.y; r[6] = (_Float16)b.z; r[7] = (_Float16)b.w;
  return r;
}

// z inputs pre-scaled by log2e (2*log2e for g-gate) -> exp2-based activations.
__device__ __forceinline__ float lstm_act(float zi, float zf, float zg, float zo, float& cc) {
  const float ig = __builtin_amdgcn_rcpf(1.0f + __builtin_amdgcn_exp2f(-zi));
  const float fg = __builtin_amdgcn_rcpf(1.0f + __builtin_amdgcn_exp2f(-zf));
  const float gg = 1.0f - 2.0f * __builtin_amdgcn_rcpf(1.0f + __builtin_amdgcn_exp2f(zg));
  const float og = __builtin_amdgcn_rcpf(1.0f + __builtin_amdgcn_exp2f(-zo));
  cc = fg * cc + ig * gg;
  const float tc = 1.0f - 2.0f * __builtin_amdgcn_rcpf(1.0f + __builtin_amdgcn_exp2f(cc * (2.0f * LOG2E)));
  return og * tc;
}

// 1024 blocks x 256 thr (4 waves) -> 4 independent blocks/CU = 4 chains/SIMD.
// Block = 4 batches; A/D row = 4*s + q (batch s, time-offset q); one full-M=16
// xproj volley per 4 steps fills zacc regs 0..3 with xw[t..t+3]; each step's
// recurrent MFMA updates only reg q (h rows for q'!=q are zero). One cell state
// per thread (batch g16, hidden n) -> 5 transcendentals/step.
// R8 fixes vs R7: (1) hbuf XOR-swizzled (chunk ^= row&7) -> no 16-way conflicts;
// (2) wih B-frags live in LDS (lane-stride-16B, conflict-free, read 1x/pack)
// -> live regs ~95, no scratch spill.
__global__ __launch_bounds__(256, 4)
void lstm_q4s(const float* __restrict__ x, const float* __restrict__ w_ih,
              const float* __restrict__ w_hh, const float* __restrict__ b_ih,
              const float* __restrict__ b_hh, const float* __restrict__ w_clf,
              const float* __restrict__ b_clf, float* __restrict__ out) {
  __shared__ f16x8 wlds[4][4][2][64];    // 32 KB: per-wave wih B-frags
  __shared__ ushort_t hbuf[2][16][64];   // 4 KB: fp16 h, XOR-swizzled chunks
  __shared__ float red[64][5];

  const int tid = threadIdx.x;
  const int l   = tid & 63;
  const int w   = tid >> 6;        // n-strip id (wave)
  const int r15 = l & 15;          // A/D-row role; D-col role
  const int g16 = l >> 4;          // k-group role; D row-group = BATCH
  const int n   = w * 16 + r15;    // hidden index

  const float gscale[4] = {LOG2E, LOG2E, 2.0f * LOG2E, LOG2E};

  // ---- whh B-frags in registers; wih B-frags into LDS (read 1x per pack) ----
  f16x8 whh[4][2];
  float biasv[4];
#pragma unroll
  for (int c = 0; c < 4; ++c) {
    const float s = gscale[c];
    const float* wr = w_hh + (size_t)(c * 64 + n) * 64;
#pragma unroll
    for (int kc = 0; kc < 2; ++kc) {
      float4 v0 = *(const float4*)(wr + kc * 32 + g16 * 8);
      float4 v1 = *(const float4*)(wr + kc * 32 + g16 * 8 + 4);
      v0.x *= s; v0.y *= s; v0.z *= s; v0.w *= s;
      v1.x *= s; v1.y *= s; v1.z *= s; v1.w *= s;
      whh[c][kc] = cvt8h(v0, v1);
    }
    const float* wir = w_ih + (size_t)(c * 64 + n) * IN_DIM;
    {
      float4 v0 = *(const float4*)(wir + g16 * 8);   // k = 8*g16..+8 <= 31
      float4 v1 = *(const float4*)(wir + g16 * 8 + 4);
      v0.x *= s; v0.y *= s; v0.z *= s; v0.w *= s;
      v1.x *= s; v1.y *= s; v1.z *= s; v1.w *= s;
      wlds[w][c][0][l] = cvt8h(v0, v1);
    }
    {
      float4 v0 = make_float4(0, 0, 0, 0), v1 = make_float4(0, 0, 0, 0);
      if (g16 == 0) {                                // k = 32..39
        v0 = *(const float4*)(wir + 32);
        v1 = *(const float4*)(wir + 36);
        v0.x *= s; v0.y *= s; v0.z *= s; v0.w *= s;
        v1.x *= s; v1.y *= s; v1.z *= s; v1.w *= s;
      }
      wlds[w][c][1][l] = cvt8h(v0, v1);
    }
    biasv[c] = (b_ih[c * 64 + n] + b_hh[c * 64 + n]) * s;
  }

  // zero both h buffers
  {
    uint_t* hz = (uint_t*)&hbuf[0][0][0];
    for (int i = tid; i < 1024; i += 256) hz[i] = 0;
  }
  __syncthreads();

  // x A-provider mapping: lane provides A row r15 = 4*s_a + q_a
  const int s_a = r15 >> 2;
  const int q_a = r15 & 3;
  const float* xbase = x + (size_t)(blockIdx.x * 4 + s_a) * T_STEPS * IN_DIM;

  float4 xa0, xa1, xb0 = make_float4(0, 0, 0, 0), xb1 = make_float4(0, 0, 0, 0);
  {
    const float* xp = xbase + q_a * IN_DIM + g16 * 8;
    xa0 = *(const float4*)xp;
    xa1 = *(const float4*)(xp + 4);
    if (g16 == 0) {
      xb0 = *(const float4*)(xbase + q_a * IN_DIM + 32);
      xb1 = *(const float4*)(xbase + q_a * IN_DIM + 36);
    }
  }

  f32x4 zacc[4];
  float cc = 0.f, a = 0.f;
  float wc_cur = w_clf[n];
  const int wrb = g16 * 4;

  // loop-invariant swizzled LDS addresses
  ushort_t* const hflat = &hbuf[0][0][0];
  const int rsw = r15 & 7;
  const f16x8* const rb0k0 = (const f16x8*)&hflat[       r15 * 64 + ((g16    ) ^ rsw) * 8];
  const f16x8* const rb0k1 = (const f16x8*)&hflat[       r15 * 64 + ((g16 + 4) ^ rsw) * 8];
  const f16x8* const rb1k0 = (const f16x8*)&hflat[1024 + r15 * 64 + ((g16    ) ^ rsw) * 8];
  const f16x8* const rb1k1 = (const f16x8*)&hflat[1024 + r15 * 64 + ((g16 + 4) ^ rsw) * 8];
  const int nc = n >> 3, ne = n & 7;
#define WIDX(BUF, R) ((BUF) * 1024 + (R) * 64 + ((nc ^ ((R) & 7)) * 8) + ne)
  const int w_q0 = WIDX(1, wrb + 1), z_q0 = WIDX(1, wrb + 3);
  const int w_q1 = WIDX(0, wrb + 2), z_q1 = WIDX(0, wrb + 0);
  const int w_q2 = WIDX(1, wrb + 3), z_q2 = WIDX(1, wrb + 1);
  const int w_q3 = WIDX(0, wrb + 0), z_q3 = WIDX(0, wrb + 2);
#undef WIDX

#define QSTEP(Q, PK0, PK1, WI, ZI)                                                \
  {                                                                               \
    const int t = t0 + Q;                                                         \
    f16x8 ah0 = *(PK0);                                                           \
    f16x8 ah1 = *(PK1);                                                           \
    _Pragma("unroll")                                                             \
    for (int c = 0; c < 4; ++c) {                                                 \
      zacc[c] = __builtin_amdgcn_mfma_f32_16x16x32_f16(ah0, whh[c][0], zacc[c], 0, 0, 0); \
      zacc[c] = __builtin_amdgcn_mfma_f32_16x16x32_f16(ah1, whh[c][1], zacc[c], 0, 0, 0); \
    }                                                                             \
    const float wcn = (t + 1 < T_STEPS) ? w_clf[(t + 1) * 64 + n] : wc_cur;       \
    const float h = lstm_act(zacc[0][Q], zacc[1][Q], zacc[2][Q], zacc[3][Q], cc); \
    a += h * wc_cur;                                                              \
    wc_cur = wcn;                                                                 \
    union { _Float16 hf; ushort_t u; } cv;                                        \
    cv.hf = (_Float16)h;                                                          \
    hflat[WI] = cv.u;                                                             \
    hflat[ZI] = 0;                                                                \
    asm volatile("s_waitcnt lgkmcnt(0)\n\ts_barrier" ::: "memory");               \
  }

  for (int p = 0; p <= 75; ++p) {
    const int t0 = 4 * p;
    // ---- q = 0: xproj volley (wih from LDS) + recurrence ----
    {
      f16x8 ah0 = *rb0k0;
      f16x8 ah1 = *rb0k1;
      const f16x8 xf0 = cvt8h(xa0, xa1);
      const f16x8 xf1 = cvt8h(xb0, xb1);
#pragma unroll
      for (int c = 0; c < 4; ++c) {
        zacc[c] = (f32x4){biasv[c], biasv[c], biasv[c], biasv[c]};
        zacc[c] = __builtin_amdgcn_mfma_f32_16x16x32_f16(xf0, wlds[w][c][0][l], zacc[c], 0, 0, 0);
        zacc[c] = __builtin_amdgcn_mfma_f32_16x16x32_f16(xf1, wlds[w][c][1][l], zacc[c], 0, 0, 0);
      }
      // prefetch x for next pack (stays in flight across barriers)
      if (t0 + 4 < T_STEPS) {
        const int tq = t0 + 4 + q_a;
        const int tm = (tq <= T_STEPS - 1) ? tq : T_STEPS - 1;
        const float* xp = xbase + tm * IN_DIM + g16 * 8;
        xa0 = *(const float4*)xp;
        xa1 = *(const float4*)(xp + 4);
        if (g16 == 0) {
          xb0 = *(const float4*)(xbase + tm * IN_DIM + 32);
          xb1 = *(const float4*)(xbase + tm * IN_DIM + 36);
        }
      }
#pragma unroll
      for (int c = 0; c < 4; ++c) {
        zacc[c] = __builtin_amdgcn_mfma_f32_16x16x32_f16(ah0, whh[c][0], zacc[c], 0, 0, 0);
        zacc[c] = __builtin_amdgcn_mfma_f32_16x16x32_f16(ah1, whh[c][1], zacc[c], 0, 0, 0);
      }
      const float wcn = (t0 + 1 < T_STEPS) ? w_clf[(t0 + 1) * 64 + n] : wc_cur;
      const float h = lstm_act(zacc[0][0], zacc[1][0], zacc[2][0], zacc[3][0], cc);
      a += h * wc_cur;
      wc_cur = wcn;
      union { _Float16 hf; ushort_t u; } cv;
      cv.hf = (_Float16)h;
      hflat[w_q0] = cv.u;
      hflat[z_q0] = 0;
      if (t0 + 1 >= T_STEPS) break;    // t0 == 300 (uniform across block)
      asm volatile("s_waitcnt lgkmcnt(0)\n\ts_barrier" ::: "memory");
    }
    QSTEP(1, rb1k0, rb1k1, w_q1, z_q1)
    QSTEP(2, rb0k0, rb0k1, w_q2, z_q2)
    QSTEP(3, rb1k0, rb1k1, w_q3, z_q3)
  }
#undef QSTEP

  // ---- epilogue: reduce classifier partials over hidden dim ----
  red[n][g16] = a;
  __syncthreads();
  if (tid < 4) {
    float s = b_clf[0];
#pragma unroll 8
    for (int j = 0; j < 64; ++j) s += red[j][tid];
    out[blockIdx.x * 4 + tid] = s;
  }
}

extern "C" void kernel_launch(void* const* d_in, const int* in_sizes, int n_in,
                              void* d_out, int out_size, void* d_ws, size_t ws_size,
                              hipStream_t stream) {
  const float* x     = (const float*)d_in[0];
  const float* w_ih  = (const float*)d_in[1];
  const float* w_hh  = (const float*)d_in[2];
  const float* b_ih  = (const float*)d_in[3];
  const float* b_hh  = (const float*)d_in[4];
  const float* w_clf = (const float*)d_in[5];
  const float* b_clf = (const float*)d_in[6];
  float* out = (float*)d_out;

  lstm_q4s<<<1024, 256, 0, stream>>>(x, w_ih, w_hh, b_ih, b_hh, w_clf, b_clf, out);
}